// Round 1
// 583.935 us; speedup vs baseline: 1.1092x; 1.1092x over previous
//
#include <hip/hip_runtime.h>
#include <hip/hip_bf16.h>

#define B_ 8
#define L_ 2048
#define D_ 1024
#define CTX_ELEMS (B_ * L_ * D_)   /* 16,777,216 */

typedef __bf16 bf16x8 __attribute__((ext_vector_type(8)));
typedef float f32x4 __attribute__((ext_vector_type(4)));
typedef unsigned short u16x8 __attribute__((ext_vector_type(8)));
typedef unsigned short u16x4 __attribute__((ext_vector_type(4)));

typedef __attribute__((address_space(1))) void GV;
typedef __attribute__((address_space(3))) void LV;
// async global->LDS, 16B per lane; LDS dst = wave-uniform base + lane*16
#define GLL16(g, l) __builtin_amdgcn_global_load_lds((GV*)(g), (LV*)(l), 16, 0, 0)

__device__ __forceinline__ unsigned short f2bf(float f) {
    union { float f; unsigned u; } c; c.f = f;
    unsigned u = c.u;
    u += 0x7fffu + ((u >> 16) & 1u);   // RNE
    return (unsigned short)(u >> 16);
}

// ---------------------------------------------------------------------------
// fp32 -> bf16 bulk convert.  blockIdx.y selects tensor.
// ---------------------------------------------------------------------------
__global__ __launch_bounds__(256) void cvt_kernel(
    const float* __restrict__ x, const float* __restrict__ y,
    const float* __restrict__ Wk, const float* __restrict__ Wv,
    const float* __restrict__ Wq,
    unsigned short* __restrict__ xb, unsigned short* __restrict__ yb,
    unsigned short* __restrict__ wkb, unsigned short* __restrict__ wvb,
    unsigned short* __restrict__ wqb)
{
    const float* src; unsigned short* dst; int n4;
    switch (blockIdx.y) {
        case 0:  src = x;  dst = xb;  n4 = CTX_ELEMS / 4; break;
        case 1:  src = y;  dst = yb;  n4 = CTX_ELEMS / 4; break;
        case 2:  src = Wk; dst = wkb; n4 = D_ * D_ / 4;   break;
        case 3:  src = Wv; dst = wvb; n4 = D_ * D_ / 4;   break;
        default: src = Wq; dst = wqb; n4 = D_ * D_ / 4;   break;
    }
    const int stride = gridDim.x * 256;
    for (int i = blockIdx.x * 256 + threadIdx.x; i < n4; i += stride) {
        float4 f = ((const float4*)src)[i];
        u16x4 o = { f2bf(f.x), f2bf(f.y), f2bf(f.z), f2bf(f.w) };
        ((u16x4*)dst)[i] = o;
    }
}

// ---------------------------------------------------------------------------
// Deep-pipelined 256x256 NT GEMM core (out[m][n] = sum_k A[m][k]*B[n][k]):
//   BK=32, 8 waves (2Mx4N), per-wave 128x64 output, acc[8][4] f32x4.
//   LDS: depth-4 ring of 32KB slots (A 16KB + B 16KB) = 128KB dynamic.
//   Per K-tile: 2 phases of {ds_read frags | 2x global_load_lds | s_barrier |
//   lgkmcnt(0)+sched_barrier | setprio(1) 16xMFMA setprio(0) | s_barrier}.
//   Counted s_waitcnt vmcnt(8) once per K-tile -- never vmcnt(0) in steady
//   state (T3+T4).  Frag reads bank-conflict-free via 16B-slot XOR swizzle
//   (row>>1)&3, realized by pre-swizzling the per-lane GLOBAL source address
//   so the global_load_lds destination stays linear (both-sides-or-neither).
//   WAR safety on slot reuse: stage of tile t+3 (slot (t-1)&3) is issued >=2
//   barriers after every wave's reads of tile t-1 completed (own lgkmcnt(0)
//   precedes the joining barrier).
// ---------------------------------------------------------------------------
#define BARx()  __builtin_amdgcn_s_barrier()
#define LGKM0() do { asm volatile("s_waitcnt lgkmcnt(0)" ::: "memory"); \
                     __builtin_amdgcn_sched_barrier(0); } while (0)
#define PRIO(p) __builtin_amdgcn_s_setprio(p)

#define G256_VARS \
    const int tid = threadIdx.x; \
    const int wave = tid >> 6, lane = tid & 63; \
    const int wr = wave >> 2, wc = wave & 3; \
    const int lrow = lane & 15, quad = lane >> 4; \
    const int srow = lane >> 2; \
    const int colsw = ((lane & 3) ^ ((lane >> 3) & 3)) << 3; \
    const int colgrp = (quad ^ ((lrow >> 1) & 3)) << 4; \
    const int pA = (wr * 128 + lrow) * 64 + colgrp; \
    const int pB = (wc * 64 + lrow) * 64 + colgrp;

#define STAGE_A(s, kk) do { \
    GLL16(srcA0 + (kk), smem + (s) * 16384 + wave * 1024); \
    GLL16(srcA1 + (kk), smem + (s) * 16384 + wave * 1024 + 512); } while (0)
#define STAGE_B(s, kk) do { \
    GLL16(srcB0 + (kk), smem + (s) * 16384 + 8192 + wave * 1024); \
    GLL16(srcB1 + (kk), smem + (s) * 16384 + 8192 + wave * 1024 + 512); } while (0)

#define G256_KLOOP(Ag, lda, Bg, ldb, NT) \
    const unsigned short* srcA0 = (Ag) + (size_t)(m0 + wave * 32 + srow) * (lda) + colsw; \
    const unsigned short* srcA1 = srcA0 + 16 * (size_t)(lda); \
    const unsigned short* srcB0 = (Bg) + (size_t)(n0 + wave * 32 + srow) * (ldb) + colsw; \
    const unsigned short* srcB1 = srcB0 + 16 * (size_t)(ldb); \
    f32x4 acc[8][4]; \
    _Pragma("unroll") \
    for (int i = 0; i < 8; i++) \
        _Pragma("unroll") \
        for (int j = 0; j < 4; j++) acc[i][j] = (f32x4){0.f, 0.f, 0.f, 0.f}; \
    _Pragma("unroll") \
    for (int s = 0; s < 3; s++) { STAGE_A(s, s * 32); STAGE_B(s, s * 32); } \
    asm volatile("s_waitcnt vmcnt(8)" ::: "memory"); \
    BARx(); \
    for (int t = 0; t < (NT); ++t) { \
        const char* As = (const char*)smem + (t & 3) * 32768; \
        const char* Bs = As + 16384; \
        const int ss = (t + 3) & 3, kk = (t + 3) * 32; \
        bf16x8 av[8], bv[4]; \
        _Pragma("unroll") \
        for (int i = 0; i < 4; i++) av[i] = *(const bf16x8*)(As + pA + i * 1024); \
        _Pragma("unroll") \
        for (int j = 0; j < 4; j++) bv[j] = *(const bf16x8*)(Bs + pB + j * 1024); \
        if (t < (NT) - 3) STAGE_A(ss, kk); \
        BARx(); LGKM0(); \
        PRIO(1); \
        _Pragma("unroll") \
        for (int i = 0; i < 4; i++) \
            _Pragma("unroll") \
            for (int j = 0; j < 4; j++) \
                acc[i][j] = __builtin_amdgcn_mfma_f32_16x16x32_bf16(av[i], bv[j], acc[i][j], 0, 0, 0); \
        PRIO(0); \
        BARx(); \
        _Pragma("unroll") \
        for (int i = 4; i < 8; i++) av[i] = *(const bf16x8*)(As + pA + i * 1024); \
        if (t < (NT) - 3) STAGE_B(ss, kk); \
        BARx(); LGKM0(); \
        PRIO(1); \
        _Pragma("unroll") \
        for (int i = 4; i < 8; i++) \
            _Pragma("unroll") \
            for (int j = 0; j < 4; j++) \
                acc[i][j] = __builtin_amdgcn_mfma_f32_16x16x32_bf16(av[i], bv[j], acc[i][j], 0, 0, 0); \
        PRIO(0); \
        if (t < (NT) - 3)      { asm volatile("s_waitcnt vmcnt(8)" ::: "memory"); } \
        else if (t == (NT) - 3) { asm volatile("s_waitcnt vmcnt(4)" ::: "memory"); } \
        else if (t == (NT) - 2) { asm volatile("s_waitcnt vmcnt(0)" ::: "memory"); } \
        if (t < (NT) - 1) BARx(); \
    }

// ---------------------------------------------------------------------------
// Projections (all NT GEMMs, K=1024):
//   z=0: kb[l][d]  = x @ Wk^T   (A=x  M=16384, B=Wk N=1024)
//   z=1: vtb[d][l] = Wv @ x^T   (A=Wv M=1024,  B=x  N=16384)  -> v transposed
//   z=2: qb[l][d]  = y @ Wq^T   (A=y  M=16384, B=Wq N=1024)
// Epilogue restages the 256x256 bf16 tile through LDS (quad-XOR swizzled)
// so global stores are 512B-contiguous u16x8.
// ---------------------------------------------------------------------------
__global__ __launch_bounds__(512, 2) void proj_kernel(
    const unsigned short* __restrict__ xb, const unsigned short* __restrict__ yb,
    const unsigned short* __restrict__ wkb, const unsigned short* __restrict__ wvb,
    const unsigned short* __restrict__ wqb,
    unsigned short* __restrict__ kb, unsigned short* __restrict__ qb,
    unsigned short* __restrict__ vtb)
{
    extern __shared__ unsigned short smem[];   // 128KB dynamic
    const int z = blockIdx.z;
    const int lin = blockIdx.x;                // 0..255
    int m0, n0;
    const unsigned short *Ag, *Bg;
    if (z == 0)      { Ag = xb;  Bg = wkb; m0 = (lin >> 2) * 256; n0 = (lin & 3) * 256; }
    else if (z == 1) { Ag = wvb; Bg = xb;  m0 = (lin & 3) * 256;  n0 = (lin >> 2) * 256; }
    else             { Ag = yb;  Bg = wqb; m0 = (lin >> 2) * 256; n0 = (lin & 3) * 256; }

    G256_VARS
    G256_KLOOP(Ag, D_, Bg, D_, 32)

    unsigned short* base; size_t ostride;
    if (z == 1) {
        base = vtb + (size_t)(n0 >> 11) * D_ * L_ + (size_t)m0 * L_ + (n0 & 2047);
        ostride = L_;
    } else {
        base = ((z == 0) ? kb : qb) + (size_t)m0 * D_ + n0;
        ostride = D_;
    }

    // acc -> LDS bf16 (swizzled: byte ^= quad<<5 kills the b16-scatter
    // bank conflict) -> 512B-contiguous u16x8 global stores
    __syncthreads();
#pragma unroll
    for (int i = 0; i < 8; i++)
#pragma unroll
        for (int j = 0; j < 4; j++)
#pragma unroll
            for (int r = 0; r < 4; r++) {
                const int row = wr * 128 + i * 16 + quad * 4 + r;
                const int col = wc * 64 + j * 16 + lrow;
                const int off = (row * 512 + col * 2) ^ ((row & 12) << 3);
                *(unsigned short*)((char*)smem + off) = f2bf(acc[i][j][r]);
            }
    __syncthreads();
#pragma unroll
    for (int c = 0; c < 16; c++) {
        const int idx = c * 512 + tid;          // 0..8191
        const int rr = idx >> 5, cc = idx & 31; // row 0..255, 16B-chunk 0..31
        const int off = (rr * 512 + cc * 16) ^ ((rr & 12) << 3);
        *(u16x8*)(base + (size_t)rr * ostride + cc * 8)
            = *(const u16x8*)((const char*)smem + off);
    }
}

// ---------------------------------------------------------------------------
// scores[b][m][n] = (1/32) sum_d q[m][d] k[n][d]  -> fp32 attn
// ---------------------------------------------------------------------------
__global__ __launch_bounds__(512, 2) void scores_kernel(
    const unsigned short* __restrict__ qb, const unsigned short* __restrict__ kb,
    float* __restrict__ attn)
{
    extern __shared__ unsigned short smem[];
    const int bz = blockIdx.z;
    const unsigned short* Ag = qb + (size_t)bz * L_ * D_;
    const unsigned short* Bg = kb + (size_t)bz * L_ * D_;
    float* out = attn + (size_t)bz * L_ * L_;
    const int lin = blockIdx.x;                 // 0..63
    const int m0 = (lin >> 3) * 256, n0 = (lin & 7) * 256;

    G256_VARS
    G256_KLOOP(Ag, D_, Bg, D_, 32)

#pragma unroll
    for (int i = 0; i < 8; i++) {
        const int m = m0 + wr * 128 + i * 16 + quad * 4;
#pragma unroll
        for (int j = 0; j < 4; j++) {
            const int n = n0 + wc * 64 + j * 16 + lrow;
#pragma unroll
            for (int r = 0; r < 4; r++)
                out[(size_t)(m + r) * L_ + n] = acc[i][j][r] * 0.03125f;
        }
    }
}

// ---------------------------------------------------------------------------
// row softmax in place + bf16 copy.  Masked query rows -> exactly 1/2048.
// ---------------------------------------------------------------------------
__global__ __launch_bounds__(256) void softmax_kernel(
    float* __restrict__ attn, const int* __restrict__ lens,
    unsigned short* __restrict__ attn_bf)
{
    const int r  = blockIdx.x;
    const int b  = r >> 11;
    const int qi = r & 2047;
    float4* rowp = (float4*)(attn + (size_t)r * L_);
    u16x4*  rowb = (u16x4*)(attn_bf + (size_t)r * L_);
    const int tid = threadIdx.x;

    if (qi >= lens[b]) {
        const float u = 1.0f / 2048.0f;
        const unsigned short us = f2bf(u);
        const float4 uf = {u, u, u, u};
        const u16x4 ub = {us, us, us, us};
        rowp[tid] = uf; rowp[tid + 256] = uf;
        rowb[tid] = ub; rowb[tid + 256] = ub;
        return;
    }

    float4 v0 = rowp[tid], v1 = rowp[tid + 256];

    float m = fmaxf(fmaxf(fmaxf(v0.x, v0.y), fmaxf(v0.z, v0.w)),
                    fmaxf(fmaxf(v1.x, v1.y), fmaxf(v1.z, v1.w)));
#pragma unroll
    for (int off = 32; off > 0; off >>= 1) m = fmaxf(m, __shfl_xor(m, off, 64));

    __shared__ float redm[4];
    __shared__ float reds[4];
    const int wave = tid >> 6, lane = tid & 63;
    if (lane == 0) redm[wave] = m;
    __syncthreads();
    m = fmaxf(fmaxf(redm[0], redm[1]), fmaxf(redm[2], redm[3]));

    v0.x = __expf(v0.x - m); v0.y = __expf(v0.y - m);
    v0.z = __expf(v0.z - m); v0.w = __expf(v0.w - m);
    v1.x = __expf(v1.x - m); v1.y = __expf(v1.y - m);
    v1.z = __expf(v1.z - m); v1.w = __expf(v1.w - m);
    float s = (v0.x + v0.y) + (v0.z + v0.w) + (v1.x + v1.y) + (v1.z + v1.w);
#pragma unroll
    for (int off = 32; off > 0; off >>= 1) s += __shfl_xor(s, off, 64);
    if (lane == 0) reds[wave] = s;
    __syncthreads();
    s = reds[0] + reds[1] + reds[2] + reds[3];

    const float inv = 1.0f / s;
    v0.x *= inv; v0.y *= inv; v0.z *= inv; v0.w *= inv;
    v1.x *= inv; v1.y *= inv; v1.z *= inv; v1.w *= inv;
    rowp[tid] = v0; rowp[tid + 256] = v1;
    u16x4 b0 = { f2bf(v0.x), f2bf(v0.y), f2bf(v0.z), f2bf(v0.w) };
    u16x4 b1 = { f2bf(v1.x), f2bf(v1.y), f2bf(v1.z), f2bf(v1.w) };
    rowb[tid] = b0; rowb[tid + 256] = b1;
}

// ---------------------------------------------------------------------------
// context[b][m][n] = sum_l attn[m][l] * v[l][n] = NT GEMM(attn_bf, v^T), K=2048
// ---------------------------------------------------------------------------
__global__ __launch_bounds__(512, 2) void context_kernel(
    const unsigned short* __restrict__ attn_bf, const unsigned short* __restrict__ vtb,
    float* __restrict__ ctx)
{
    extern __shared__ unsigned short smem[];
    const int bz = blockIdx.z;
    const unsigned short* Ag = attn_bf + (size_t)bz * L_ * L_;  // [2048][2048]
    const unsigned short* Bg = vtb + (size_t)bz * D_ * L_;      // [1024][2048]
    float* out = ctx + (size_t)bz * L_ * D_;
    const int lin = blockIdx.x;                 // 0..31
    const int m0 = (lin >> 2) * 256, n0 = (lin & 3) * 256;

    G256_VARS
    G256_KLOOP(Ag, L_, Bg, L_, 64)

#pragma unroll
    for (int i = 0; i < 8; i++) {
        const int m = m0 + wr * 128 + i * 16 + quad * 4;
#pragma unroll
        for (int j = 0; j < 4; j++) {
            const int n = n0 + wc * 64 + j * 16 + lrow;
#pragma unroll
            for (int r = 0; r < 4; r++)
                out[(size_t)(m + r) * D_ + n] = acc[i][j][r];
        }
    }
}

// ---------------------------------------------------------------------------
extern "C" void kernel_launch(void* const* d_in, const int* in_sizes, int n_in,
                              void* d_out, int out_size, void* d_ws, size_t ws_size,
                              hipStream_t stream) {
    const float* x    = (const float*)d_in[0];
    const int*   lens = (const int*)d_in[1];
    const float* y    = (const float*)d_in[2];
    const float* Wk   = (const float*)d_in[3];
    const float* Wv   = (const float*)d_in[4];
    const float* Wq   = (const float*)d_in[5];

    float* ctx  = (float*)d_out;                 // [B,L,D] fp32
    float* attn = (float*)d_out + CTX_ELEMS;     // [B,L,L] fp32

    // ws: kb, qb, vtb (bf16).  attn_bf aliases kb+qb after scores (exactly spans both).
    unsigned short* kb      = (unsigned short*)d_ws;
    unsigned short* qb      = kb + CTX_ELEMS;
    unsigned short* vtb     = qb + CTX_ELEMS;
    unsigned short* attn_bf = (unsigned short*)d_ws;

    // bf16 staging of inputs parked inside d_out's attn region (dead until scores)
    unsigned short* xb  = (unsigned short*)attn;
    unsigned short* yb  = xb + CTX_ELEMS;
    unsigned short* wkb = yb + CTX_ELEMS;
    unsigned short* wvb = wkb + D_ * D_;
    unsigned short* wqb = wvb + D_ * D_;

    // 128KB dynamic LDS opt-in (host state change, not a stream op; capture-safe)
    (void)hipFuncSetAttribute((const void*)proj_kernel,
                              hipFuncAttributeMaxDynamicSharedMemorySize, 131072);
    (void)hipFuncSetAttribute((const void*)scores_kernel,
                              hipFuncAttributeMaxDynamicSharedMemorySize, 131072);
    (void)hipFuncSetAttribute((const void*)context_kernel,
                              hipFuncAttributeMaxDynamicSharedMemorySize, 131072);

    cvt_kernel<<<dim3(2048, 5), 256, 0, stream>>>(x, y, Wk, Wv, Wq,
                                                  xb, yb, wkb, wvb, wqb);
    proj_kernel<<<dim3(256, 1, 3), 512, 131072, stream>>>(xb, yb, wkb, wvb, wqb,
                                                          kb, qb, vtb);
    scores_kernel<<<dim3(64, 1, 8), 512, 131072, stream>>>(qb, kb, attn);
    softmax_kernel<<<dim3(B_ * L_), 256, 0, stream>>>(attn, lens, attn_bf);
    context_kernel<<<dim3(32, 1, 8), 512, 131072, stream>>>(attn_bf, vtb, ctx);
}

// Round 2
// 565.337 us; speedup vs baseline: 1.1457x; 1.0329x over previous
//
#include <hip/hip_runtime.h>
#include <hip/hip_bf16.h>

#define B_ 8
#define L_ 2048
#define D_ 1024
#define CTX_ELEMS (B_ * L_ * D_)   /* 16,777,216 */

typedef __bf16 bf16x8 __attribute__((ext_vector_type(8)));
typedef float f32x4 __attribute__((ext_vector_type(4)));
typedef unsigned short u16x8 __attribute__((ext_vector_type(8)));
typedef unsigned short u16x4 __attribute__((ext_vector_type(4)));

typedef __attribute__((address_space(1))) void GV;
typedef __attribute__((address_space(3))) void LV;
// async global->LDS, 16B per lane; LDS dst = wave-uniform base + lane*16
#define GLL16(g, l) __builtin_amdgcn_global_load_lds((GV*)(g), (LV*)(l), 16, 0, 0)

__device__ __forceinline__ unsigned short f2bf(float f) {
    union { float f; unsigned u; } c; c.f = f;
    unsigned u = c.u;
    u += 0x7fffu + ((u >> 16) & 1u);   // RNE
    return (unsigned short)(u >> 16);
}

// ---------------------------------------------------------------------------
// fp32 -> bf16 bulk convert.  blockIdx.y selects tensor.
// ---------------------------------------------------------------------------
__global__ __launch_bounds__(256) void cvt_kernel(
    const float* __restrict__ x, const float* __restrict__ y,
    const float* __restrict__ Wk, const float* __restrict__ Wv,
    const float* __restrict__ Wq,
    unsigned short* __restrict__ xb, unsigned short* __restrict__ yb,
    unsigned short* __restrict__ wkb, unsigned short* __restrict__ wvb,
    unsigned short* __restrict__ wqb)
{
    const float* src; unsigned short* dst; int n4;
    switch (blockIdx.y) {
        case 0:  src = x;  dst = xb;  n4 = CTX_ELEMS / 4; break;
        case 1:  src = y;  dst = yb;  n4 = CTX_ELEMS / 4; break;
        case 2:  src = Wk; dst = wkb; n4 = D_ * D_ / 4;   break;
        case 3:  src = Wv; dst = wvb; n4 = D_ * D_ / 4;   break;
        default: src = Wq; dst = wqb; n4 = D_ * D_ / 4;   break;
    }
    const int stride = gridDim.x * 256;
    for (int i = blockIdx.x * 256 + threadIdx.x; i < n4; i += stride) {
        float4 f = ((const float4*)src)[i];
        u16x4 o = { f2bf(f.x), f2bf(f.y), f2bf(f.z), f2bf(f.w) };
        ((u16x4*)dst)[i] = o;
    }
}

// ---------------------------------------------------------------------------
// m201-style 256x256 NT GEMM core (out[m][n] = sum_k A[m][k]*B[n][k]):
//   BK=64, 512 thr (8 waves, 2Mx4N), per-wave 128x64 out, acc[8][4] f32x4.
//   LDS 128KB: 2 buffers x {A: 2 K-halves x 256x32, B: same} (16KB per half).
//   4 phases per K-tile; phase (ih, ks) = {4-12 ds_read_b128 | stage 1
//   half-tile | s_barrier | lgkmcnt(0)+sched_barrier | setprio(1) 16 MFMA
//   setprio(0) | [vmcnt] | s_barrier}.  K-half slots are phase-dead ->
//   re-stage is WAR-safe one barrier after last read.
//   Stage schedule: t.1: (t+1).Ak1, t.2: (t+1).Bk1, t.3: (t+2).Ak0,
//   t.4: (t+2).Bk0.  Counted waits vmcnt(8) at phases 2 & 4 only (each half
//   lands >=5 phases before its deadline); drains 8->4->0 on last 2 tiles.
//   LDS zero-conflict via 16B-chunk XOR (chunk ^= (row>>1)&3), realized as
//   pre-swizzled GLOBAL source + linear gload_lds dest + swizzled ds_read.
// ---------------------------------------------------------------------------
#define BARx()  __builtin_amdgcn_s_barrier()
#define LGKM0() do { asm volatile("s_waitcnt lgkmcnt(0)" ::: "memory"); \
                     __builtin_amdgcn_sched_barrier(0); } while (0)
#define PRIO(p) __builtin_amdgcn_s_setprio(p)
#define VMW8 asm volatile("s_waitcnt vmcnt(8)" ::: "memory")
#define VMW4 asm volatile("s_waitcnt vmcnt(4)" ::: "memory")
#define VMW0 asm volatile("s_waitcnt vmcnt(0)" ::: "memory")

#define G256_VARS \
    const int tid = threadIdx.x; \
    const int wave = tid >> 6, lane = tid & 63; \
    const int wr = wave >> 2, wc = wave & 3; \
    const int lrow = lane & 15, quad = lane >> 4; \
    const int sg_r = lane >> 2; \
    const int sg_c8 = ((lane & 3) ^ ((lane >> 3) & 3)) << 3; \
    const int fsw = (quad ^ ((lrow >> 1) & 3)) << 4; \
    const int pA = (wr * 128 + lrow) * 64 + fsw; \
    const int pB = (wc * 64 + lrow) * 64 + fsw; \
    char* smemc = (char*)smem;

// stage one 16KB half-tile (256 rows x 32 cols): 2 x GLL16 per wave
#define STAGE(TT, KH, SRCP, LD, REGOFF) do { \
    const unsigned short* _s = (SRCP) + (size_t)(wave * 32 + sg_r) * (LD) \
                               + (size_t)(TT) * 64 + (KH) * 32 + sg_c8; \
    char* _d = smemc + ((TT) & 1) * 65536 + (REGOFF) + (KH) * 16384 + wave * 2048; \
    GLL16(_s, _d); \
    GLL16(_s + (size_t)16 * (LD), _d + 1024); } while (0)
#define STA(TT, KH) STAGE(TT, KH, Ag2, lda_, 0)
#define STB(TT, KH) STAGE(TT, KH, Bg2, ldb_, 32768)

#define MF16(IOFF, BV) \
    _Pragma("unroll") for (int i = 0; i < 4; i++) \
        _Pragma("unroll") for (int j = 0; j < 4; j++) \
            acc[(IOFF) + i][j] = __builtin_amdgcn_mfma_f32_16x16x32_bf16( \
                av[i], BV[j], acc[(IOFF) + i][j], 0, 0, 0);

#define TILE(T, NT) do { \
    const char* Ab = smemc + ((T) & 1) * 65536; \
    const char* Bb = Ab + 32768; \
    bf16x8 av[4], bv0[4], bv1[4]; \
    /* phase 1: rows 0-63, K-half 0 */ \
    _Pragma("unroll") for (int i = 0; i < 4; i++) \
        av[i] = *(const bf16x8*)(Ab + pA + i * 1024); \
    _Pragma("unroll") for (int j = 0; j < 4; j++) \
        bv0[j] = *(const bf16x8*)(Bb + pB + j * 1024); \
    if ((T) + 1 < (NT)) STA((T) + 1, 1); \
    BARx(); LGKM0(); PRIO(1); \
    MF16(0, bv0); \
    PRIO(0); BARx(); \
    /* phase 2: rows 64-127, K-half 0 */ \
    _Pragma("unroll") for (int i = 0; i < 4; i++) \
        av[i] = *(const bf16x8*)(Ab + pA + (i + 4) * 1024); \
    if ((T) + 1 < (NT)) STB((T) + 1, 1); \
    BARx(); LGKM0(); PRIO(1); \
    MF16(4, bv0); \
    PRIO(0); \
    if ((T) < (NT) - 1) { VMW8; } else { VMW0; } \
    BARx(); \
    /* phase 3: rows 0-63, K-half 1 */ \
    _Pragma("unroll") for (int i = 0; i < 4; i++) \
        av[i] = *(const bf16x8*)(Ab + 16384 + pA + i * 1024); \
    _Pragma("unroll") for (int j = 0; j < 4; j++) \
        bv1[j] = *(const bf16x8*)(Bb + 16384 + pB + j * 1024); \
    if ((T) + 2 < (NT)) STA((T) + 2, 0); \
    BARx(); LGKM0(); PRIO(1); \
    MF16(0, bv1); \
    PRIO(0); BARx(); \
    /* phase 4: rows 64-127, K-half 1 */ \
    _Pragma("unroll") for (int i = 0; i < 4; i++) \
        av[i] = *(const bf16x8*)(Ab + 16384 + pA + (i + 4) * 1024); \
    if ((T) + 2 < (NT)) STB((T) + 2, 0); \
    BARx(); LGKM0(); PRIO(1); \
    MF16(4, bv1); \
    PRIO(0); \
    if ((T) < (NT) - 2) { VMW8; } else if ((T) == (NT) - 2) { VMW4; } else { VMW0; } \
    BARx(); \
} while (0)

// prologue issue order matches steady-state deadlines:
// [Ak0,Bk0,Ak1,Bk1 of tile0; Ak0,Bk0 of tile1], then vmcnt(8) guards tile0.Kh0
#define G256_KLOOP(NT) \
    f32x4 acc[8][4]; \
    _Pragma("unroll") for (int i = 0; i < 8; i++) \
        _Pragma("unroll") for (int j = 0; j < 4; j++) \
            acc[i][j] = (f32x4){0.f, 0.f, 0.f, 0.f}; \
    STA(0, 0); STB(0, 0); STA(0, 1); STB(0, 1); STA(1, 0); STB(1, 0); \
    VMW8; BARx(); \
    for (int T = 0; T < (NT); ++T) { TILE(T, (NT)); }

// ---------------------------------------------------------------------------
// Projections (all NT GEMMs, K=1024):
//   z=0: kb[l][d]  = x @ Wk^T   (A=x  M=16384, B=Wk N=1024)
//   z=1: vtb[d][l] = Wv @ x^T   (A=Wv M=1024,  B=x  N=16384)  -> v transposed
//   z=2: qb[l][d]  = y @ Wq^T   (A=y  M=16384, B=Wq N=1024)
// XCD-locality remap: the 4 blocks sharing a big-dim panel land on one XCD
// (lin&7) so their K-lockstep slices stay L2-resident.
// ---------------------------------------------------------------------------
__global__ __launch_bounds__(512, 2) void proj_kernel(
    const unsigned short* __restrict__ xb, const unsigned short* __restrict__ yb,
    const unsigned short* __restrict__ wkb, const unsigned short* __restrict__ wvb,
    const unsigned short* __restrict__ wqb,
    unsigned short* __restrict__ kb, unsigned short* __restrict__ qb,
    unsigned short* __restrict__ vtb)
{
    extern __shared__ unsigned short smem[];   // 128KB dynamic
    const int z = blockIdx.z;
    const int lin = blockIdx.x;                // 0..255
    const int xcd = lin & 7, tt = lin >> 3;    // 0..31
    const int big = xcd * 8 + (tt >> 2);       // 0..63, same-panel -> same XCD
    const int sml = tt & 3;                    // 0..3
    int m0, n0;
    const unsigned short *Ag, *Bg;
    if (z == 0)      { Ag = xb;  Bg = wkb; m0 = big * 256; n0 = sml * 256; }
    else if (z == 1) { Ag = wvb; Bg = xb;  m0 = sml * 256; n0 = big * 256; }
    else             { Ag = yb;  Bg = wqb; m0 = big * 256; n0 = sml * 256; }

    G256_VARS
    const int lda_ = D_, ldb_ = D_;
    const unsigned short* Ag2 = Ag + (size_t)m0 * lda_;
    const unsigned short* Bg2 = Bg + (size_t)n0 * ldb_;

    G256_KLOOP(16)

    unsigned short* base; size_t ostride;
    if (z == 1) {
        base = vtb + (size_t)(n0 >> 11) * D_ * L_ + (size_t)m0 * L_ + (n0 & 2047);
        ostride = L_;
    } else {
        base = ((z == 0) ? kb : qb) + (size_t)m0 * D_ + n0;
        ostride = D_;
    }

    // acc -> LDS bf16 (swizzled: byte ^= (row&12)<<3 kills the b16-scatter
    // bank conflict) -> 512B-contiguous u16x8 global stores
    __syncthreads();
#pragma unroll
    for (int i = 0; i < 8; i++)
#pragma unroll
        for (int j = 0; j < 4; j++)
#pragma unroll
            for (int r = 0; r < 4; r++) {
                const int row = wr * 128 + i * 16 + quad * 4 + r;
                const int col = wc * 64 + j * 16 + lrow;
                const int off = (row * 512 + col * 2) ^ ((row & 12) << 3);
                *(unsigned short*)((char*)smem + off) = f2bf(acc[i][j][r]);
            }
    __syncthreads();
#pragma unroll
    for (int c = 0; c < 16; c++) {
        const int idx = c * 512 + tid;          // 0..8191
        const int rr = idx >> 5, cc = idx & 31; // row 0..255, 16B-chunk 0..31
        const int off = (rr * 512 + cc * 16) ^ ((rr & 12) << 3);
        *(u16x8*)(base + (size_t)rr * ostride + cc * 8)
            = *(const u16x8*)((const char*)smem + off);
    }
}

// ---------------------------------------------------------------------------
// scores[b][m][n] = (1/32) sum_d q[m][d] k[n][d]  -> fp32 attn
// n0 = x&7: each XCD keeps one k-panel resident per batch.
// ---------------------------------------------------------------------------
__global__ __launch_bounds__(512, 2) void scores_kernel(
    const unsigned short* __restrict__ qb, const unsigned short* __restrict__ kb,
    float* __restrict__ attn)
{
    extern __shared__ unsigned short smem[];
    const int bz = blockIdx.z;
    const unsigned short* Ag = qb + (size_t)bz * L_ * D_;
    const unsigned short* Bg = kb + (size_t)bz * L_ * D_;
    float* out = attn + (size_t)bz * L_ * L_;
    const int x = blockIdx.x;                   // 0..63
    const int m0 = (x >> 3) * 256, n0 = (x & 7) * 256;

    G256_VARS
    const int lda_ = D_, ldb_ = D_;
    const unsigned short* Ag2 = Ag + (size_t)m0 * lda_;
    const unsigned short* Bg2 = Bg + (size_t)n0 * ldb_;

    G256_KLOOP(16)

#pragma unroll
    for (int i = 0; i < 8; i++) {
        const int m = m0 + wr * 128 + i * 16 + quad * 4;
#pragma unroll
        for (int j = 0; j < 4; j++) {
            const int n = n0 + wc * 64 + j * 16 + lrow;
#pragma unroll
            for (int r = 0; r < 4; r++)
                out[(size_t)(m + r) * L_ + n] = acc[i][j][r] * 0.03125f;
        }
    }
}

// ---------------------------------------------------------------------------
// row softmax in place + bf16 copy.  Masked query rows -> exactly 1/2048.
// ---------------------------------------------------------------------------
__global__ __launch_bounds__(256) void softmax_kernel(
    float* __restrict__ attn, const int* __restrict__ lens,
    unsigned short* __restrict__ attn_bf)
{
    const int r  = blockIdx.x;
    const int b  = r >> 11;
    const int qi = r & 2047;
    float4* rowp = (float4*)(attn + (size_t)r * L_);
    u16x4*  rowb = (u16x4*)(attn_bf + (size_t)r * L_);
    const int tid = threadIdx.x;

    if (qi >= lens[b]) {
        const float u = 1.0f / 2048.0f;
        const unsigned short us = f2bf(u);
        const float4 uf = {u, u, u, u};
        const u16x4 ub = {us, us, us, us};
        rowp[tid] = uf; rowp[tid + 256] = uf;
        rowb[tid] = ub; rowb[tid + 256] = ub;
        return;
    }

    float4 v0 = rowp[tid], v1 = rowp[tid + 256];

    float m = fmaxf(fmaxf(fmaxf(v0.x, v0.y), fmaxf(v0.z, v0.w)),
                    fmaxf(fmaxf(v1.x, v1.y), fmaxf(v1.z, v1.w)));
#pragma unroll
    for (int off = 32; off > 0; off >>= 1) m = fmaxf(m, __shfl_xor(m, off, 64));

    __shared__ float redm[4];
    __shared__ float reds[4];
    const int wave = tid >> 6, lane = tid & 63;
    if (lane == 0) redm[wave] = m;
    __syncthreads();
    m = fmaxf(fmaxf(redm[0], redm[1]), fmaxf(redm[2], redm[3]));

    v0.x = __expf(v0.x - m); v0.y = __expf(v0.y - m);
    v0.z = __expf(v0.z - m); v0.w = __expf(v0.w - m);
    v1.x = __expf(v1.x - m); v1.y = __expf(v1.y - m);
    v1.z = __expf(v1.z - m); v1.w = __expf(v1.w - m);
    float s = (v0.x + v0.y) + (v0.z + v0.w) + (v1.x + v1.y) + (v1.z + v1.w);
#pragma unroll
    for (int off = 32; off > 0; off >>= 1) s += __shfl_xor(s, off, 64);
    if (lane == 0) reds[wave] = s;
    __syncthreads();
    s = reds[0] + reds[1] + reds[2] + reds[3];

    const float inv = 1.0f / s;
    v0.x *= inv; v0.y *= inv; v0.z *= inv; v0.w *= inv;
    v1.x *= inv; v1.y *= inv; v1.z *= inv; v1.w *= inv;
    rowp[tid] = v0; rowp[tid + 256] = v1;
    u16x4 b0 = { f2bf(v0.x), f2bf(v0.y), f2bf(v0.z), f2bf(v0.w) };
    u16x4 b1 = { f2bf(v1.x), f2bf(v1.y), f2bf(v1.z), f2bf(v1.w) };
    rowb[tid] = b0; rowb[tid + 256] = b1;
}

// ---------------------------------------------------------------------------
// context[b][m][n] = sum_l attn[m][l] * v[l][n] = NT GEMM(attn_bf, v^T), K=2048
// m0 = x&7: the 4 n-readers of each attn-panel share one XCD's L2.
// ---------------------------------------------------------------------------
__global__ __launch_bounds__(512, 2) void context_kernel(
    const unsigned short* __restrict__ attn_bf, const unsigned short* __restrict__ vtb,
    float* __restrict__ ctx)
{
    extern __shared__ unsigned short smem[];
    const int bz = blockIdx.z;
    const unsigned short* Ag = attn_bf + (size_t)bz * L_ * L_;  // [2048][2048]
    const unsigned short* Bg = vtb + (size_t)bz * D_ * L_;      // [1024][2048]
    float* out = ctx + (size_t)bz * L_ * D_;
    const int x = blockIdx.x;                   // 0..31
    const int m0 = (x & 7) * 256, n0 = (x >> 3) * 256;

    G256_VARS
    const int lda_ = L_, ldb_ = L_;
    const unsigned short* Ag2 = Ag + (size_t)m0 * lda_;
    const unsigned short* Bg2 = Bg + (size_t)n0 * ldb_;

    G256_KLOOP(32)

#pragma unroll
    for (int i = 0; i < 8; i++) {
        const int m = m0 + wr * 128 + i * 16 + quad * 4;
#pragma unroll
        for (int j = 0; j < 4; j++) {
            const int n = n0 + wc * 64 + j * 16 + lrow;
#pragma unroll
            for (int r = 0; r < 4; r++)
                out[(size_t)(m + r) * D_ + n] = acc[i][j][r];
        }
    }
}

// ---------------------------------------------------------------------------
extern "C" void kernel_launch(void* const* d_in, const int* in_sizes, int n_in,
                              void* d_out, int out_size, void* d_ws, size_t ws_size,
                              hipStream_t stream) {
    const float* x    = (const float*)d_in[0];
    const int*   lens = (const int*)d_in[1];
    const float* y    = (const float*)d_in[2];
    const float* Wk   = (const float*)d_in[3];
    const float* Wv   = (const float*)d_in[4];
    const float* Wq   = (const float*)d_in[5];

    float* ctx  = (float*)d_out;                 // [B,L,D] fp32
    float* attn = (float*)d_out + CTX_ELEMS;     // [B,L,L] fp32

    // ws: kb, qb, vtb (bf16).  attn_bf aliases kb+qb after scores (exactly spans both).
    unsigned short* kb      = (unsigned short*)d_ws;
    unsigned short* qb      = kb + CTX_ELEMS;
    unsigned short* vtb     = qb + CTX_ELEMS;
    unsigned short* attn_bf = (unsigned short*)d_ws;

    // bf16 staging of inputs parked inside d_out's attn region (dead until scores)
    unsigned short* xb  = (unsigned short*)attn;
    unsigned short* yb  = xb + CTX_ELEMS;
    unsigned short* wkb = yb + CTX_ELEMS;
    unsigned short* wvb = wkb + D_ * D_;
    unsigned short* wqb = wvb + D_ * D_;

    // 128KB dynamic LDS opt-in (host state change, not a stream op; capture-safe)
    (void)hipFuncSetAttribute((const void*)proj_kernel,
                              hipFuncAttributeMaxDynamicSharedMemorySize, 131072);
    (void)hipFuncSetAttribute((const void*)scores_kernel,
                              hipFuncAttributeMaxDynamicSharedMemorySize, 131072);
    (void)hipFuncSetAttribute((const void*)context_kernel,
                              hipFuncAttributeMaxDynamicSharedMemorySize, 131072);

    cvt_kernel<<<dim3(2048, 5), 256, 0, stream>>>(x, y, Wk, Wv, Wq,
                                                  xb, yb, wkb, wvb, wqb);
    proj_kernel<<<dim3(256, 1, 3), 512, 131072, stream>>>(xb, yb, wkb, wvb, wqb,
                                                          kb, qb, vtb);
    scores_kernel<<<dim3(64, 1, 8), 512, 131072, stream>>>(qb, kb, attn);
    softmax_kernel<<<dim3(B_ * L_), 256, 0, stream>>>(attn, lens, attn_bf);
    context_kernel<<<dim3(32, 1, 8), 512, 131072, stream>>>(attn_bf, vtb, ctx);
}